// Round 7
// baseline (167.386 us; speedup 1.0000x reference)
//
#include <hip/hip_runtime.h>

typedef __attribute__((ext_vector_type(8))) short short8;
typedef __attribute__((ext_vector_type(4))) float floatx4;
typedef unsigned int uint;
typedef unsigned short ushort;
typedef __attribute__((ext_vector_type(4))) uint uintx4;

#define NTOK   8192
#define DIN    1024
#define DOUT   1024
#define NJ     96        // 84 decision nodes (12 trees x 7) + 12 gates
#define TOKPB  32        // tokens per block (k_routed) -> 256 blocks = 1/CU
#define XSTR   136       // k_routed LDS row stride (bf16 elems)
#define DSTR   97        // decis LDS row stride (f32)
#define SSTR   85        // sdec LDS row stride (f32)
#define OSTR   104       // k_out LDS row stride (bf16 elems): 52 dw, breaks 96-elem bank pathology
#define LOT_H  (DOUT * NJ)

static __device__ inline ushort f2b(float f) {
    uint u = __builtin_bit_cast(uint, f);
    u = u + 0x7fffu + ((u >> 16) & 1u);   // RNE
    return (ushort)(u >> 16);
}
static __device__ inline uint pack2(float a, float b) {
    return (uint)f2b(a) | ((uint)f2b(b) << 16);
}

// ---------------------------------------------------------------------------
// k_prep: build bf16 staging buffers with coalesced 16B stores.
//  job A (36864 thr): lot[h][d][k0..7] <- lo[h][k][d]   (transpose, uint4 out)
//  job B (12288 thr): wcat[r][c0..7]   <- dw/gw f32     (pack, uint4 out)
// ---------------------------------------------------------------------------
__global__ __launch_bounds__(256) void k_prep(const float* __restrict__ lo,
                                              const float* __restrict__ dw,
                                              const float* __restrict__ gw,
                                              ushort* __restrict__ lot,
                                              ushort* __restrict__ wcat) {
    int i = blockIdx.x * 256 + threadIdx.x;
    if (i < 36864) {                       // 3 * 1024 * 12
        int h   = i / 12288;
        int rem = i - h * 12288;
        int d   = rem / 12;
        int kg  = rem - d * 12;
        const float* src = lo + (size_t)h * LOT_H + (size_t)kg * 8 * DOUT + d;
        ushort tmp[8];
#pragma unroll
        for (int j = 0; j < 8; ++j) tmp[j] = f2b(src[j * DOUT]);
        *(uintx4*)(lot + (size_t)h * LOT_H + d * NJ + kg * 8) = *(uintx4*)tmp;
    } else {                               // 12288 threads for wcat
        int j = i - 36864;                 // 0..12287
        int r = j >> 7, cg = j & 127;      // r<96, cg*8 elems
        const float* src = (r < 84) ? (dw + (size_t)r * DIN) : (gw + (size_t)(r - 84) * DIN);
        src += cg * 8;
        float4 v0 = *(const float4*)(src);
        float4 v1 = *(const float4*)(src + 4);
        uintx4 p;
        p.x = pack2(v0.x, v0.y); p.y = pack2(v0.z, v0.w);
        p.z = pack2(v1.x, v1.y); p.w = pack2(v1.z, v1.w);
        *(uintx4*)(wcat + (size_t)r * DIN + cg * 8) = p;
    }
}

// ---------------------------------------------------------------------------
// k_routed: decisions+gates GEMM (MFMA bf16, x prefetch-pipelined) + routing
// epilogue -> routed[8192][96] bf16.  32 tokens/block, 256 blocks.
// ---------------------------------------------------------------------------
__global__ __launch_bounds__(256) void k_routed(
    const float* __restrict__ x,     // [8192][1024] f32
    const ushort* __restrict__ wcat, // [96][1024] bf16
    const float* __restrict__ db,    // [84]
    const float* __restrict__ ntl,   // [84]
    const float* __restrict__ gb,    // [12]
    const int*   __restrict__ pi,    // [8][3]
    const float* __restrict__ pd,    // [8][3]
    ushort* __restrict__ routed)     // [8192][96]
{
    __shared__ __attribute__((aligned(16))) char smem[34816];
    __shared__ float invt[84];
    __shared__ float biasf[96];
    __shared__ int   pis[24];
    __shared__ float pds[24];

    ushort* xl = (ushort*)smem;                        // [32][XSTR]
    ushort* wl = (ushort*)(smem + TOKPB * XSTR * 2);   // [96][XSTR]
    float*  decis = (float*)smem;                      // [32][DSTR] (reuse)
    float*  sdecs = (float*)(smem + TOKPB * DSTR * 4); // [32][SSTR]

    const int tid = threadIdx.x;
    const int tb  = blockIdx.x * TOKPB;

    if (tid < 84) {
        float z = ntl[tid] + 0.5413f;
        float sp = (z > 20.0f) ? z : log1pf(__expf(z));   // softplus
        invt[tid]  = 1.0f / sp;
        biasf[tid] = db[tid];
    } else if (tid < 96) {
        biasf[tid] = gb[tid - 84];
    } else if (tid < 120) {
        pis[tid - 96] = pi[tid - 96];
    } else if (tid < 144) {
        pds[tid - 120] = pd[tid - 120];
    }

    const int wave = tid >> 6, lane = tid & 63;
    const int lrow = lane & 15, quad = lane >> 4;
    const int wm = wave & 1, wn = wave >> 1;

    const int xr = tid >> 5, xc = tid & 31;   // staging coords (32 rows x 32 float4)

    floatx4 acc[3];
#pragma unroll
    for (int nt = 0; nt < 3; ++nt) acc[nt] = (floatx4)(0.0f);

    // prefetch chunk 0 of x into registers
    float4 xp[4];
#pragma unroll
    for (int i = 0; i < 4; ++i)
        xp[i] = *(const float4*)(x + (size_t)(tb + xr + i * 8) * DIN + xc * 4);

    for (int kc = 0; kc < 8; ++kc) {
        __syncthreads();   // MFMA of prev chunk done; LDS reusable
        // commit prefetched x regs -> LDS (f32 -> bf16)
#pragma unroll
        for (int i = 0; i < 4; ++i) {
            uint2 p;
            p.x = pack2(xp[i].x, xp[i].y);
            p.y = pack2(xp[i].z, xp[i].w);
            *(uint2*)(xl + (xr + i * 8) * XSTR + xc * 4) = p;
        }
        // stage w tile (bf16, from L2-resident wcat)
#pragma unroll
        for (int i = 0; i < 6; ++i) {
            int idx = tid + 256 * i;
            int r = idx >> 4, c = idx & 15;
            uintx4 v = *(const uintx4*)(wcat + (size_t)r * DIN + kc * 128 + c * 8);
            *(uintx4*)(wl + r * XSTR + c * 8) = v;
        }
        __syncthreads();
        // issue next x prefetch; overlaps the MFMA section below
        if (kc < 7) {
#pragma unroll
            for (int i = 0; i < 4; ++i)
                xp[i] = *(const float4*)(x + (size_t)(tb + xr + i * 8) * DIN + (kc + 1) * 128 + xc * 4);
        }

        short8 a[4];
#pragma unroll
        for (int kt = 0; kt < 4; ++kt)
            a[kt] = *(const short8*)(xl + (wm * 16 + lrow) * XSTR + kt * 32 + quad * 8);
#pragma unroll
        for (int nt = 0; nt < 3; ++nt) {
#pragma unroll
            for (int kt = 0; kt < 4; ++kt) {
                short8 b = *(const short8*)(wl + (wn * 48 + nt * 16 + lrow) * XSTR + kt * 32 + quad * 8);
                acc[nt] = __builtin_amdgcn_mfma_f32_16x16x32_bf16(a[kt], b, acc[nt], 0, 0, 0);
            }
        }
    }

    __syncthreads();
    // C/D: col = lane&15 (j), row = quad*4+reg (token)
#pragma unroll
    for (int nt = 0; nt < 3; ++nt)
#pragma unroll
        for (int r = 0; r < 4; ++r)
            decis[(wm * 16 + quad * 4 + r) * DSTR + wn * 48 + nt * 16 + lrow] = acc[nt][r];
    __syncthreads();

    // sigmoid over 32 tokens x 84 nodes
#pragma unroll
    for (int i = 0; i < 11; ++i) {
        int idx = tid + 256 * i;
        if (idx < TOKPB * 84) {
            int tk = idx / 84, nd = idx - tk * 84;
            float dv = (decis[tk * DSTR + nd] + biasf[nd]) * invt[nd];
            sdecs[tk * SSTR + nd] = 1.0f / (1.0f + __expf(-dv));
        }
    }
    __syncthreads();

    // 256 threads = 32 tokens x 8 leaves
    {
        const int tk = tid >> 3, l = tid & 7;
        float g[12], gm = -1e30f;
#pragma unroll
        for (int tt = 0; tt < 12; ++tt) {
            g[tt] = decis[tk * DSTR + 84 + tt] + biasf[84 + tt];
            gm = fmaxf(gm, g[tt]);
        }
        float gs = 0.0f;
#pragma unroll
        for (int tt = 0; tt < 12; ++tt) { g[tt] = __expf(g[tt] - gm); gs += g[tt]; }
        float ginv = 1.0f / gs;

        const int   n0 = pis[l * 3 + 0], n1 = pis[l * 3 + 1], n2 = pis[l * 3 + 2];
        const float d0 = pds[l * 3 + 0], d1 = pds[l * 3 + 1], d2 = pds[l * 3 + 2];
        const float* sd = sdecs + tk * SSTR;
        ushort* dst = routed + (size_t)(tb + tk) * NJ + l;
#pragma unroll
        for (int t = 0; t < 12; ++t) {
            float s0 = sd[t * 7 + n0], s1 = sd[t * 7 + n1], s2 = sd[t * 7 + n2];
            float pb = g[t] * ginv
                     * (d0 * s0 + (1.0f - d0) * (1.0f - s0))
                     * (d1 * s1 + (1.0f - d1) * (1.0f - s1))
                     * (d2 * s2 + (1.0f - d2) * (1.0f - s2));
            dst[t * 8] = f2b(pb);
        }
    }
}

// ---------------------------------------------------------------------------
// k_out: out[h][tok][d] = sum_k routed[tok][k] * lot[h][d][k]  (MFMA, K=96)
// A and B tiles are contiguous 12 KB regions -> coalesced LDS staging.
// ---------------------------------------------------------------------------
__global__ __launch_bounds__(256) void k_out(
    const ushort* __restrict__ routed,  // [8192][96] bf16
    const ushort* __restrict__ lot,     // [3][1024][96] bf16
    float* __restrict__ out)            // [3][8192][1024] f32
{
    __shared__ __attribute__((aligned(16))) ushort al[64 * OSTR];  // [tok][k]
    __shared__ __attribute__((aligned(16))) ushort bl[64 * OSTR];  // [d][k]

    const int tid = threadIdx.x;
    const int tb = blockIdx.x * 64;
    const int d0 = blockIdx.y * 64;
    const int h  = blockIdx.z;

    const ushort* asrc = routed + (size_t)tb * NJ;                   // 12 KB contiguous
    const ushort* bsrc = lot + ((size_t)h * DOUT + d0) * NJ;         // 12 KB contiguous
#pragma unroll
    for (int i = 0; i < 3; ++i) {
        int flat = tid + i * 256;               // 768 uint4 per tile
        int row = flat / 12, col = (flat % 12) * 8;
        uintx4 va = *(const uintx4*)(asrc + flat * 8);
        *(uintx4*)(al + row * OSTR + col) = va;
        uintx4 vb = *(const uintx4*)(bsrc + flat * 8);
        *(uintx4*)(bl + row * OSTR + col) = vb;
    }
    __syncthreads();

    const int wave = tid >> 6, lane = tid & 63;
    const int lrow = lane & 15, quad = lane >> 4;

    short8 a[3];
#pragma unroll
    for (int kk = 0; kk < 3; ++kk)
        a[kk] = *(const short8*)(al + (wave * 16 + lrow) * OSTR + kk * 32 + quad * 8);

    floatx4 acc[4];
#pragma unroll
    for (int nt = 0; nt < 4; ++nt) {
        acc[nt] = (floatx4)(0.0f);
#pragma unroll
        for (int kk = 0; kk < 3; ++kk) {
            short8 b = *(const short8*)(bl + (nt * 16 + lrow) * OSTR + kk * 32 + quad * 8);
            acc[nt] = __builtin_amdgcn_mfma_f32_16x16x32_bf16(a[kk], b, acc[nt], 0, 0, 0);
        }
    }
#pragma unroll
    for (int nt = 0; nt < 4; ++nt) {
        int d = d0 + nt * 16 + lrow;
#pragma unroll
        for (int r = 0; r < 4; ++r) {
            int tok = tb + wave * 16 + quad * 4 + r;
            out[((size_t)h * NTOK + tok) * DOUT + d] = acc[nt][r];
        }
    }
}

// ---------------------------------------------------------------------------
extern "C" void kernel_launch(void* const* d_in, const int* in_sizes, int n_in,
                              void* d_out, int out_size, void* d_ws, size_t ws_size,
                              hipStream_t stream) {
    const float* x   = (const float*)d_in[0];
    const float* dw  = (const float*)d_in[1];
    const float* db  = (const float*)d_in[2];
    const float* ntl = (const float*)d_in[3];
    const float* gw  = (const float*)d_in[4];
    const float* gb  = (const float*)d_in[5];
    const float* lo  = (const float*)d_in[6];
    const int*   pi  = (const int*)d_in[7];
    const float* pd  = (const float*)d_in[8];
    float* out = (float*)d_out;

    ushort* routed = (ushort*)d_ws;                    // 8192*96*2  = 1.57 MB
    ushort* lot    = routed + (size_t)NTOK * NJ;       // 3*98304*2  = 0.59 MB
    ushort* wcat   = lot + (size_t)3 * LOT_H;          // 96*1024*2  = 0.20 MB

    k_prep<<<dim3(192), dim3(256), 0, stream>>>(lo, dw, gw, lot, wcat);
    k_routed<<<dim3(NTOK / TOKPB), dim3(256), 0, stream>>>(x, wcat, db, ntl, gb, pi, pd, routed);
    k_out<<<dim3(NTOK / 64, DOUT / 64, 3), dim3(256), 0, stream>>>(routed, lot, out);
}